// Round 11
// baseline (559.482 us; speedup 1.0000x reference)
//
#include <hip/hip_runtime.h>
#include <hip/hip_bf16.h>
#include <cstdint>
#include <cstddef>

#define N_ACT 200000
#define CH 128
#define NOFF 27
#define TM 128   // 2x2 wave split (64 rows x 64 couts/wave) at TM=128:
                 // LDS/block-k 96 KB (vs 160 at 1x4) AND B total 2.7 GB
                 // (vs 5.4 at TM=64). Register cliff avoided by streaming
                 // B per-kk (4 live frags, 16 VGPR) -> ~115 regs/wave.

typedef __bf16 v8bf __attribute__((ext_vector_type(8)));
typedef float v4f __attribute__((ext_vector_type(4)));

__device__ __forceinline__ unsigned short f2bf(float f) {
    union { float f; unsigned int u; } x; x.f = f;
    unsigned int lsb = (x.u >> 16) & 1u;
    x.u += 0x7fffu + lsb;            // round-to-nearest-even
    return (unsigned short)(x.u >> 16);
}

// async global->LDS. LDS dest is WAVE-UNIFORM base + lane*size.
__device__ __forceinline__ void gload_lds16(const void* g, void* l) {
    __builtin_amdgcn_global_load_lds(
        (const __attribute__((address_space(1))) unsigned int*)g,
        (__attribute__((address_space(3))) unsigned int*)l,
        16, 0, 0);
}
__device__ __forceinline__ void gload_lds4(const void* g, void* l) {
    __builtin_amdgcn_global_load_lds(
        (const __attribute__((address_space(1))) unsigned int*)g,
        (__attribute__((address_space(3))) unsigned int*)l,
        4, 0, 0);
}

// K1: fused prep_w (blocks 0..26) + cast_feat (grid-stride, remaining blocks)
__global__ void prep_and_cast(const float* __restrict__ features,
                              const float* __restrict__ W,
                              unsigned short* __restrict__ feat_bf,
                              unsigned short* __restrict__ Wtp,
                              float* __restrict__ stats,
                              float* __restrict__ zpage) {
    int t = threadIdx.x;
    if (blockIdx.x < NOFF) {
        // ---- prep_w: pack W[k][cin][cout] fp32 into fragment-order bf16:
        //   Wtp[(k*4+q)*4096 + (jkk*64 + lane)*8 + e]
        // value = W[k][kk*32+quad*8+e][q*32+j*16+lr].
        int k = blockIdx.x;
        if (k == 0 && t < 2 * CH) stats[t] = 0.0f;   // sums + sumsq
        if (k == 0 && t < 64) zpage[t] = 0.0f;       // zero row for gathers
        const float* wk = W + (size_t)k * CH * CH;
        for (int g = t; g < 2048; g += 256) {
            int q = g >> 9, r = g & 511;
            int jkk = r >> 6, lane = r & 63;
            int j = jkk >> 2, kk = jkk & 3;
            int lr = lane & 15, quad = lane >> 4;
            int cout = q * 32 + j * 16 + lr;
            int cin0 = kk * 32 + quad * 8;
            unsigned int wbuf[4];
            #pragma unroll
            for (int h = 0; h < 4; ++h) {
                unsigned short lo = f2bf(wk[(size_t)(cin0 + 2*h)     * CH + cout]);
                unsigned short hi = f2bf(wk[(size_t)(cin0 + 2*h + 1) * CH + cout]);
                wbuf[h] = (unsigned)lo | ((unsigned)hi << 16);
            }
            *(uint4*)(Wtp + ((size_t)(k * 4 + q) << 12)
                          + (size_t)(jkk * 64 + lane) * 8)
                = make_uint4(wbuf[0], wbuf[1], wbuf[2], wbuf[3]);
        }
        return;
    }
    // ---- cast_feat: fp32 -> bf16, 8 elems/thread/iter, grid-stride
    const long long total = (long long)N_ACT * CH / 8;   // 3.2M groups
    long long stride = (long long)(gridDim.x - NOFF) * blockDim.x;
    for (long long i = (long long)(blockIdx.x - NOFF) * blockDim.x + t;
         i < total; i += stride) {
        long long base = i * 8;
        const float4* p = (const float4*)(features + base);
        float4 a = p[0], b = p[1];
        unsigned int w0 = (unsigned)f2bf(a.x) | ((unsigned)f2bf(a.y) << 16);
        unsigned int w1 = (unsigned)f2bf(a.z) | ((unsigned)f2bf(a.w) << 16);
        unsigned int w2 = (unsigned)f2bf(b.x) | ((unsigned)f2bf(b.y) << 16);
        unsigned int w3 = (unsigned)f2bf(b.z) | ((unsigned)f2bf(b.w) << 16);
        *(uint4*)(feat_bf + base) = make_uint4(w0, w1, w2, w3);
    }
}

// K2: TM=128, 2x2 wave grid, kk-outer streamed-B MFMA phase.
// Wave (wr,wc) computes rows [wr*64,+64) x couts [wc*64,+64).
// Per k per wave: 16 LDS b128 A-reads (half of R9) + 16 streamed B loads
// (L1/L2-hot Wtp, inside the MFMA phase, only 4 live frags) + 64 MFMAs.
// Stage phase (between barriers) is pure DMA: stageA + idxDMA, zero VGPR.
// LDS 33 KB -> 4 blocks/CU; regs ~115/wave -> 4 waves/SIMD.
__global__ __launch_bounds__(256, 4) void conv_mfma(
        const unsigned short* __restrict__ feat,   // [N][128] bf16
        const int* __restrict__ nbr,               // [27][N]
        const unsigned short* __restrict__ Wtp,    // packed (see prep)
        const unsigned short* __restrict__ zpage,  // 256 B of zeros
        float* __restrict__ out,                   // [N][128] conv result
        float* __restrict__ stats) {               // sums[128], sumsq[128]
    __shared__ __bf16 As[TM * CH];                 // 32 KB, rotated chunks
    __shared__ int idxS[2][TM];                    // 1 KB idx double-buffer

    const int t    = threadIdx.x;
    const int row0 = blockIdx.x * TM;
    const int wid  = t >> 6;
    const int lane = t & 63;
    const int lr   = lane & 15;
    const int quad = lane >> 4;
    const int wr   = wid >> 1;      // row-half of this wave   (0..1)
    const int wc   = wid & 1;       // cout-half of this wave  (0..1)
    const int sc   = lane & 15;     // dest chunk this lane stages
    const int lhi  = lane >> 4;     // row-within-wave-group
    const int wv4  = wid * 4;       // wave's 4-row staging group base

    v4f acc[4][4];
    #pragma unroll
    for (int i = 0; i < 4; ++i)
        #pragma unroll
        for (int j = 0; j < 4; ++j)
            acc[i][j] = (v4f){0.f, 0.f, 0.f, 0.f};

    // DMA 128 neighbor indices of offset k into idxS[slot] (wave 0 only).
    // Tail rows clamped; garbage masked in the epilogue (grow < N_ACT).
    auto idxDMA = [&](int k, int slot) {
        const int* src = nbr + (size_t)k * N_ACT;
        int r0 = min(row0 + lane,      N_ACT - 1);
        int r1 = min(row0 + 64 + lane, N_ACT - 1);
        gload_lds4(src + r0, &idxS[slot][0]);
        gload_lds4(src + r1, &idxS[slot][64]);
    };
    // 8 direct-to-LDS gathers: dest row p*16+wv4+lhi chunk sc (uniform
    // base + lane*16). Source inverse-rotated: global chunk (sc-row)&15,
    // so the MFMA read (stored chunk (kk*4+quad)&15 at row ..+lr) is the
    // R9-verified pattern.
    auto stageA = [&](int slot) {
        #pragma unroll
        for (int p = 0; p < 8; ++p) {
            int row = p * 16 + wv4 + lhi;
            int idx = idxS[slot][row];
            int gch = (sc - row) & 15;
            const unsigned short* src = (idx >= 0)
                ? feat + ((size_t)idx << 7) + gch * 8
                : zpage + gch * 8;
            gload_lds16(src, As + (size_t)(p * 16 + wv4) * CH);
        }
    };
    // kk-outer MFMA phase with streamed B: per kk load the 4 B-frags of
    // this wave's cout quarters {2wc,2wc+1} (R3/R10-verified indexing:
    // value(B4[j],lane,e) = W[kk*32+quad*8+e][wc*64+j*16+lr]), then
    // 4 i-subtiles x 4 j MFMAs. Only 4 B frags (16 VGPR) ever live.
    auto mfmaPhase = [&](int k) {
        #pragma unroll
        for (int kk = 0; kk < 4; ++kk) {
            v8bf B4[4];
            #pragma unroll
            for (int j = 0; j < 4; ++j) {
                const unsigned short* bp = Wtp
                    + ((size_t)(k * 4 + 2 * wc + (j >> 1)) << 12)
                    + (size_t)((((j & 1) * 4 + kk) * 64) + lane) * 8;
                B4[j] = *(const v8bf*)bp;
            }
            #pragma unroll
            for (int i = 0; i < 4; ++i) {
                const __bf16* rowp = As + (wr * 64 + i * 16 + lr) * CH;
                v8bf a = *(const v8bf*)(rowp + (((kk * 4 + quad + lr) & 15) << 3));
                #pragma unroll
                for (int j = 0; j < 4; ++j)
                    acc[i][j] = __builtin_amdgcn_mfma_f32_16x16x32_bf16(
                        a, B4[j], acc[i][j], 0, 0, 0);
            }
        }
    };

    // ---- prologue
    if (wid == 0) idxDMA(0, 0);
    __syncthreads();               // idx[0] landed (wave0 vmcnt drained)
    stageA(0);
    if (wid == 0) idxDMA(1, 1);
    __syncthreads();               // As + idx[1] landed

    // ---- k-loop: 2 barriers, single buffer; stage phase is pure DMA.
    // idx[k] in slot k&1, overwritten (idxDMA(k+2)) one phase after its
    // last read (stageA(k&1) during iter k-1) — disjoint within a phase.
    #pragma unroll 1
    for (int k = 0; k < NOFF; ++k) {
        mfmaPhase(k);
        if (k + 1 < NOFF) {
            __syncthreads();                       // As reads done
            stageA((k + 1) & 1);                   // DMA gathers for k+1
            if (wid == 0 && k + 2 < NOFF) idxDMA(k + 2, k & 1);
            __syncthreads();                       // vmcnt drain: all landed
        }
    }

    // ---- epilogue: store conv result + stats (direct atomics; two
    // wr-waves each add their 64-row partial per channel)
    float psum[4] = {0.f, 0.f, 0.f, 0.f};
    float psq[4]  = {0.f, 0.f, 0.f, 0.f};
    #pragma unroll
    for (int i = 0; i < 4; ++i) {
        #pragma unroll
        for (int r = 0; r < 4; ++r) {
            int grow = row0 + wr * 64 + i * 16 + quad * 4 + r;
            if (grow < N_ACT) {
                #pragma unroll
                for (int j = 0; j < 4; ++j) {
                    float v = acc[i][j][r];
                    out[(size_t)grow * CH + wc * 64 + j * 16 + lr] = v;
                    psum[j] += v;
                    psq[j]  += v * v;
                }
            }
        }
    }
    #pragma unroll
    for (int j = 0; j < 4; ++j) {
        psum[j] += __shfl_xor(psum[j], 16, 64);
        psq[j]  += __shfl_xor(psq[j], 16, 64);
        psum[j] += __shfl_xor(psum[j], 32, 64);
        psq[j]  += __shfl_xor(psq[j], 32, 64);
    }
    if (quad == 0) {
        #pragma unroll
        for (int j = 0; j < 4; ++j) {
            int c = wc * 64 + j * 16 + lr;
            atomicAdd(&stats[c],      psum[j]);
            atomicAdd(&stats[CH + c], psq[j]);
        }
    }
}

// K3: fused finalize + bn_relu. Each thread derives scale/shift for its
// 4 channels from raw sums (stats L2-hot), then grid-strides the relu.
__global__ void bn_relu(const float* __restrict__ conv,
                        const float* __restrict__ stats,
                        const float* __restrict__ gamma,
                        const float* __restrict__ beta,
                        float* __restrict__ out) {
    const long long total = (long long)N_ACT * CH / 4;   // 6.4M groups
    long long tid = (long long)blockIdx.x * blockDim.x + threadIdx.x;
    // stride is a multiple of 32 -> (i & 31) invariant across iterations
    int c4 = (int)(tid & 31) * 4;
    float sc[4], sh[4];
    const float inv_n = 1.0f / (float)N_ACT;
    #pragma unroll
    for (int j = 0; j < 4; ++j) {
        int c = c4 + j;
        float mean = stats[c] * inv_n;
        float var  = stats[CH + c] * inv_n - mean * mean;
        float s    = gamma[c] * rsqrtf(var + 1e-4f);
        sc[j] = s;
        sh[j] = beta[c] - mean * s;
    }
    long long stride = (long long)gridDim.x * blockDim.x;
    for (long long i = tid; i < total; i += stride) {
        float4 v = ((const float4*)conv)[i];
        float4 o;
        o.x = fmaxf(v.x * sc[0] + sh[0], 0.f);
        o.y = fmaxf(v.y * sc[1] + sh[1], 0.f);
        o.z = fmaxf(v.z * sc[2] + sh[2], 0.f);
        o.w = fmaxf(v.w * sc[3] + sh[3], 0.f);
        ((float4*)out)[i] = o;
    }
}

extern "C" void kernel_launch(void* const* d_in, const int* in_sizes, int n_in,
                              void* d_out, int out_size, void* d_ws, size_t ws_size,
                              hipStream_t stream) {
    const float* features = (const float*)d_in[0];
    const int*   nbr      = (const int*)d_in[1];
    const float* W        = (const float*)d_in[2];
    const float* gamma    = (const float*)d_in[3];
    const float* beta     = (const float*)d_in[4];
    float* outp = (float*)d_out;

    char* ws = (char*)d_ws;
    // layout: feat_bf16 (51,200,000 B) | Wtp (884,736 B) | conv fp32
    // (102,400,000 B) | stats (512 floats) | zero page (256 B)
    unsigned short* feat_bf = (unsigned short*)ws;
    unsigned short* Wtp     = (unsigned short*)(ws + 51200000);
    float* conv             = (float*)(ws + 51200000 + 884736);
    float* stats            = (float*)(ws + 51200000 + 884736 + 102400000);
    float* zpage            = stats + 4 * CH;

    prep_and_cast<<<NOFF + 4096, 256, 0, stream>>>(
        features, W, feat_bf, Wtp, stats, zpage);
    conv_mfma<<<(N_ACT + TM - 1) / TM, 256, 0, stream>>>(
        feat_bf, nbr, Wtp, (const unsigned short*)zpage, conv, stats);
    bn_relu<<<4096, 256, 0, stream>>>(conv, stats, gamma, beta, outp);
}

// Round 12
// 396.619 us; speedup vs baseline: 1.4106x; 1.4106x over previous
//
#include <hip/hip_runtime.h>
#include <hip/hip_bf16.h>
#include <cstdint>
#include <cstddef>

#define N_ACT 200000
#define CH 128
#define NOFF 27
#define TM 96    // TM=96 + dbuf: LDS 49 KB -> 3 blocks/CU AND pipelined
                 // staging (issue k+1 before MFMA k). Combines R5/R9's
                 // occupancy axis with R6's pipeline axis. acc 48 AGPR +
                 // B 32 VGPR ~ 118 regs.

typedef __bf16 v8bf __attribute__((ext_vector_type(8)));
typedef float v4f __attribute__((ext_vector_type(4)));

__device__ __forceinline__ unsigned short f2bf(float f) {
    union { float f; unsigned int u; } x; x.f = f;
    unsigned int lsb = (x.u >> 16) & 1u;
    x.u += 0x7fffu + lsb;            // round-to-nearest-even
    return (unsigned short)(x.u >> 16);
}

// async global->LDS. LDS dest is WAVE-UNIFORM base + lane*size.
__device__ __forceinline__ void gload_lds16(const void* g, void* l) {
    __builtin_amdgcn_global_load_lds(
        (const __attribute__((address_space(1))) unsigned int*)g,
        (__attribute__((address_space(3))) unsigned int*)l,
        16, 0, 0);
}
__device__ __forceinline__ void gload_lds4(const void* g, void* l) {
    __builtin_amdgcn_global_load_lds(
        (const __attribute__((address_space(1))) unsigned int*)g,
        (__attribute__((address_space(3))) unsigned int*)l,
        4, 0, 0);
}

// K1: fused prep_w (blocks 0..26) + cast_feat (grid-stride, remaining blocks)
__global__ void prep_and_cast(const float* __restrict__ features,
                              const float* __restrict__ W,
                              unsigned short* __restrict__ feat_bf,
                              unsigned short* __restrict__ Wtp,
                              float* __restrict__ stats,
                              float* __restrict__ zpage) {
    int t = threadIdx.x;
    if (blockIdx.x < NOFF) {
        // ---- prep_w: pack W[k][cin][cout] fp32 into fragment-order bf16:
        //   Wtp[(k*4+q)*4096 + (jkk*64 + lane)*8 + e]
        // value = W[k][kk*32+quad*8+e][q*32+j*16+lr].
        int k = blockIdx.x;
        if (k == 0 && t < 2 * CH) stats[t] = 0.0f;   // sums + sumsq
        if (k == 0 && t < 64) zpage[t] = 0.0f;       // zero row for gathers
        const float* wk = W + (size_t)k * CH * CH;
        for (int g = t; g < 2048; g += 256) {
            int q = g >> 9, r = g & 511;
            int jkk = r >> 6, lane = r & 63;
            int j = jkk >> 2, kk = jkk & 3;
            int lr = lane & 15, quad = lane >> 4;
            int cout = q * 32 + j * 16 + lr;
            int cin0 = kk * 32 + quad * 8;
            unsigned int wbuf[4];
            #pragma unroll
            for (int h = 0; h < 4; ++h) {
                unsigned short lo = f2bf(wk[(size_t)(cin0 + 2*h)     * CH + cout]);
                unsigned short hi = f2bf(wk[(size_t)(cin0 + 2*h + 1) * CH + cout]);
                wbuf[h] = (unsigned)lo | ((unsigned)hi << 16);
            }
            *(uint4*)(Wtp + ((size_t)(k * 4 + q) << 12)
                          + (size_t)(jkk * 64 + lane) * 8)
                = make_uint4(wbuf[0], wbuf[1], wbuf[2], wbuf[3]);
        }
        return;
    }
    // ---- cast_feat: fp32 -> bf16, 8 elems/thread/iter, grid-stride
    const long long total = (long long)N_ACT * CH / 8;   // 3.2M groups
    long long stride = (long long)(gridDim.x - NOFF) * blockDim.x;
    for (long long i = (long long)(blockIdx.x - NOFF) * blockDim.x + t;
         i < total; i += stride) {
        long long base = i * 8;
        const float4* p = (const float4*)(features + base);
        float4 a = p[0], b = p[1];
        unsigned int w0 = (unsigned)f2bf(a.x) | ((unsigned)f2bf(a.y) << 16);
        unsigned int w1 = (unsigned)f2bf(a.z) | ((unsigned)f2bf(a.w) << 16);
        unsigned int w2 = (unsigned)f2bf(b.x) | ((unsigned)f2bf(b.y) << 16);
        unsigned int w3 = (unsigned)f2bf(b.z) | ((unsigned)f2bf(b.w) << 16);
        *(uint4*)(feat_bf + base) = make_uint4(w0, w1, w2, w3);
    }
}

// K2: TM=96, 1x4 wave split, DOUBLE-BUFFERED pipelined staging at
// 3 blocks/CU. Per k: issue 6 DMA gathers for k+1 into As[cur^1] +
// idxDMA(k+2) (all zero-VGPR) | mfmaPhase on As[cur] covers the DMA
// latency | loadB(k+1) | ONE barrier (vmcnt drain) | swap.
// All components individually verified: TM=96 indexing (R5), pipeline +
// inverse-rotated DMA source (R6/R7), slim idx dbuf (R9).
__global__ __launch_bounds__(256, 3) void conv_mfma(
        const unsigned short* __restrict__ feat,   // [N][128] bf16
        const int* __restrict__ nbr,               // [27][N]
        const unsigned short* __restrict__ Wtp,    // packed (see prep)
        const unsigned short* __restrict__ zpage,  // 256 B of zeros
        float* __restrict__ out,                   // [N][128] conv result
        float* __restrict__ stats) {               // sums[128], sumsq[128]
    __shared__ __bf16 As[2 * TM * CH];             // 2 x 24 KB double buffer
    __shared__ int idxS[2][128];                   // 1 KB idx double-buffer

    const int t    = threadIdx.x;
    const int row0 = blockIdx.x * TM;
    const int wid  = t >> 6;
    const int lane = t & 63;
    const int lr   = lane & 15;
    const int quad = lane >> 4;
    const int sc   = lane & 15;     // dest chunk this lane stages
    const int lhi  = lane >> 4;     // row-within-wave-group
    const int wv4  = wid * 4;       // wave's 4-row staging group base

    v4f acc[6][2];
    #pragma unroll
    for (int i = 0; i < 6; ++i) {
        acc[i][0] = (v4f){0.f, 0.f, 0.f, 0.f};
        acc[i][1] = (v4f){0.f, 0.f, 0.f, 0.f};
    }

    v8bf B[8];           // B fragment set for current k

    // DMA neighbor indices of offset k into idxS[slot] (wave 0 only).
    // Rows 96..127 of the buffer are loaded-but-unused padding; tail rows
    // clamped, garbage masked in the epilogue (grow < N_ACT).
    auto idxDMA = [&](int k, int slot) {
        const int* src = nbr + (size_t)k * N_ACT;
        int r0 = min(row0 + lane,      N_ACT - 1);
        int r1 = min(row0 + 64 + lane, N_ACT - 1);
        gload_lds4(src + r0, &idxS[slot][0]);
        gload_lds4(src + r1, &idxS[slot][64]);
    };
    // 6 direct-to-LDS gathers into buffer bsel: dest row p*16+wv4+lhi,
    // chunk sc (uniform base + lane*16). Source inverse-rotated: global
    // chunk (sc-row)&15, so the MFMA read (stored chunk (kk*4+quad)&15 at
    // row ..+lr) is the verified pattern.
    auto issueStage = [&](int bsel, int sidx) {
        __bf16* dstbase = As + bsel * (TM * CH);
        #pragma unroll
        for (int p = 0; p < 6; ++p) {
            int row = p * 16 + wv4 + lhi;
            int idx = idxS[sidx][row];
            int gch = (sc - row) & 15;
            const unsigned short* src = (idx >= 0)
                ? feat + ((size_t)idx << 7) + gch * 8
                : zpage + gch * 8;
            gload_lds16(src, dstbase + (size_t)(p * 16 + wv4) * CH);
        }
    };
    auto loadB = [&](int k) {
        const unsigned short* base =
            Wtp + ((size_t)(k * 4 + wid) << 12) + (size_t)lane * 8;
        #pragma unroll
        for (int jkk = 0; jkk < 8; ++jkk)
            B[jkk] = *(const v8bf*)(base + jkk * 512);
    };
    // i-blocked: per row-subtile load 4 a-frags (16 regs), fire 8 MFMAs
    auto mfmaPhase = [&](const __bf16* buf) {
        #pragma unroll
        for (int i = 0; i < 6; ++i) {
            const __bf16* rowp = buf + (i * 16 + lr) * CH;
            v8bf a[4];
            #pragma unroll
            for (int kk = 0; kk < 4; ++kk)
                a[kk] = *(const v8bf*)(rowp + (((kk * 4 + quad + lr) & 15) << 3));
            #pragma unroll
            for (int kk = 0; kk < 4; ++kk) {
                acc[i][0] = __builtin_amdgcn_mfma_f32_16x16x32_bf16(
                    a[kk], B[kk], acc[i][0], 0, 0, 0);
                acc[i][1] = __builtin_amdgcn_mfma_f32_16x16x32_bf16(
                    a[kk], B[4 + kk], acc[i][1], 0, 0, 0);
            }
        }
    };

    // ---- prologue
    if (wid == 0) idxDMA(0, 0);
    __syncthreads();               // idx[0] landed (wave0 vmcnt drained)
    issueStage(0, 0);
    if (wid == 0) idxDMA(1, 1);
    loadB(0);
    __syncthreads();               // As[0] + idx[1] + B landed

    // ---- k-loop: ONE barrier per k. Write-after-read safety: As[cur^1]
    // was last read in iter k-1, ordered by that iter's barrier. idxS
    // slot k&1 last read by issueStage in iter k-1; overwritten here by
    // idxDMA(k+2) one barrier later; this iter's issueStage reads slot
    // (k+1)&1 — disjoint.
    int cur = 0;
    #pragma unroll 1
    for (int k = 0; k < NOFF; ++k) {
        if (k + 1 < NOFF) {
            issueStage(cur ^ 1, (k + 1) & 1);      // DMA in flight over MFMA
            if (wid == 0 && k + 2 < NOFF) idxDMA(k + 2, k & 1);
        }
        mfmaPhase(As + cur * (TM * CH));
        if (k + 1 < NOFF) {
            loadB(k + 1);          // B consumed; refill for next k
            __syncthreads();       // vmcnt drain: stage + idx + B landed
            cur ^= 1;
        }
    }

    // ---- epilogue: store conv result + stats (direct atomics)
    float psum[2] = {0.f, 0.f};
    float psq[2]  = {0.f, 0.f};
    #pragma unroll
    for (int i = 0; i < 6; ++i) {
        #pragma unroll
        for (int r = 0; r < 4; ++r) {
            int grow = row0 + i * 16 + quad * 4 + r;
            if (grow < N_ACT) {
                #pragma unroll
                for (int j = 0; j < 2; ++j) {
                    float v = acc[i][j][r];
                    out[(size_t)grow * CH + wid * 32 + j * 16 + lr] = v;
                    psum[j] += v;
                    psq[j]  += v * v;
                }
            }
        }
    }
    #pragma unroll
    for (int j = 0; j < 2; ++j) {
        psum[j] += __shfl_xor(psum[j], 16, 64);
        psq[j]  += __shfl_xor(psq[j], 16, 64);
        psum[j] += __shfl_xor(psum[j], 32, 64);
        psq[j]  += __shfl_xor(psq[j], 32, 64);
    }
    if (quad == 0) {
        #pragma unroll
        for (int j = 0; j < 2; ++j) {
            int c = wid * 32 + j * 16 + lr;
            atomicAdd(&stats[c],      psum[j]);
            atomicAdd(&stats[CH + c], psq[j]);
        }
    }
}

// K3: fused finalize + bn_relu. Each thread derives scale/shift for its
// 4 channels from raw sums (stats L2-hot), then grid-strides the relu.
__global__ void bn_relu(const float* __restrict__ conv,
                        const float* __restrict__ stats,
                        const float* __restrict__ gamma,
                        const float* __restrict__ beta,
                        float* __restrict__ out) {
    const long long total = (long long)N_ACT * CH / 4;   // 6.4M groups
    long long tid = (long long)blockIdx.x * blockDim.x + threadIdx.x;
    // stride is a multiple of 32 -> (i & 31) invariant across iterations
    int c4 = (int)(tid & 31) * 4;
    float sc[4], sh[4];
    const float inv_n = 1.0f / (float)N_ACT;
    #pragma unroll
    for (int j = 0; j < 4; ++j) {
        int c = c4 + j;
        float mean = stats[c] * inv_n;
        float var  = stats[CH + c] * inv_n - mean * mean;
        float s    = gamma[c] * rsqrtf(var + 1e-4f);
        sc[j] = s;
        sh[j] = beta[c] - mean * s;
    }
    long long stride = (long long)gridDim.x * blockDim.x;
    for (long long i = tid; i < total; i += stride) {
        float4 v = ((const float4*)conv)[i];
        float4 o;
        o.x = fmaxf(v.x * sc[0] + sh[0], 0.f);
        o.y = fmaxf(v.y * sc[1] + sh[1], 0.f);
        o.z = fmaxf(v.z * sc[2] + sh[2], 0.f);
        o.w = fmaxf(v.w * sc[3] + sh[3], 0.f);
        ((float4*)out)[i] = o;
    }
}

extern "C" void kernel_launch(void* const* d_in, const int* in_sizes, int n_in,
                              void* d_out, int out_size, void* d_ws, size_t ws_size,
                              hipStream_t stream) {
    const float* features = (const float*)d_in[0];
    const int*   nbr      = (const int*)d_in[1];
    const float* W        = (const float*)d_in[2];
    const float* gamma    = (const float*)d_in[3];
    const float* beta     = (const float*)d_in[4];
    float* outp = (float*)d_out;

    char* ws = (char*)d_ws;
    // layout: feat_bf16 (51,200,000 B) | Wtp (884,736 B) | conv fp32
    // (102,400,000 B) | stats (512 floats) | zero page (256 B)
    unsigned short* feat_bf = (unsigned short*)ws;
    unsigned short* Wtp     = (unsigned short*)(ws + 51200000);
    float* conv             = (float*)(ws + 51200000 + 884736);
    float* stats            = (float*)(ws + 51200000 + 884736 + 102400000);
    float* zpage            = stats + 4 * CH;

    prep_and_cast<<<NOFF + 4096, 256, 0, stream>>>(
        features, W, feat_bf, Wtp, stats, zpage);
    conv_mfma<<<(N_ACT + TM - 1) / TM, 256, 0, stream>>>(
        feat_bf, nbr, Wtp, (const unsigned short*)zpage, conv, stats);
    bn_relu<<<4096, 256, 0, stream>>>(conv, stats, gamma, beta, outp);
}